// Round 4
// baseline (317.024 us; speedup 1.0000x reference)
//
#include <hip/hip_runtime.h>
#include <hip/hip_bf16.h>

// Problem constants (match reference)
#define B_    32
#define NV_   50000
#define NF_   100000
#define CCLS  40
#define GPB   64                       // blocks per batch
#define TPB   256
#define NTILE ((NF_ + TPB - 1) / TPB)  // 391 face-tiles per batch

#define NLOG2E (-1.44269504088896f)    // folded into pre-sigmoid weights

typedef __attribute__((ext_vector_type(8)))  short short8v;   // 8 bf16 = 4 VGPRs
typedef __attribute__((ext_vector_type(16))) float f32x16;    // MFMA 32x32 accum

// sigmoid with pre-scaled arg: t = -log2(e)*z  ->  sigma(z) = 1/(1+2^t)
__device__ __forceinline__ float fsig2(float t) {
    return __builtin_amdgcn_rcpf(1.0f + exp2f(t));
}

__device__ __forceinline__ ushort f2bf(float x) {
    __hip_bfloat16 h = __float2bfloat16(x);   // RNE
    return *reinterpret_cast<ushort*>(&h);
}

// Kernel 1: per 256-face tile: phase A/B (geometry + layer1 -> bf16 LDS),
// phase C (layer2 on the matrix pipe: 32x32x16 bf16 MFMA, K=16 exact).
// Emits per-block partials ws[b][g][0..63]=sum sig(h2)[k]*L, ws[b][g][64]=sum L.
__global__ __launch_bounds__(TPB, 8) void face_mlp_partial(
    const float* __restrict__ V,   // [B,NV,3]
    const int*   __restrict__ F,   // [B,NF,3]
    const float* __restrict__ W1,  // [6,16]
    const float* __restrict__ b1,  // [16]
    const float* __restrict__ W2,  // [16,64]
    const float* __restrict__ b2,  // [64]
    float* __restrict__ ws)        // [B, GPB, 65]
{
    __shared__ __align__(16) ushort h1s[TPB * 16];  // bf16 h1, 32B/row (8KB)
    __shared__ __align__(16) float sLs[TPB];        // L per face
    __shared__ __align__(16) float wlds[112];       // -log2e*W1 (96), -log2e*b1 (16)
    __shared__ float red[4][64];
    __shared__ float slred[4];

    const int i   = blockIdx.x;
    // XCD-aware mapping: block i -> XCD (i&7); each XCD owns 4 batches so the
    // 4 x 600KB V-slices stay resident in its 4MB L2.
    const int xcd = i & 7;
    const int j   = i >> 3;
    const int b   = xcd + 8 * (j >> 6);
    const int g   = j & 63;
    const int tid = threadIdx.x;
    const int lane  = tid & 63;
    const int wave  = tid >> 6;
    const int ln31  = lane & 31;
    const int halfk = lane >> 5;       // k-half for A/B fragments

    const float* Vb = V + (size_t)b * NV_ * 3;
    const int*   Fb = F + (size_t)b * NF_ * 3;

    if (tid < 96)       wlds[tid] = NLOG2E * W1[tid];
    else if (tid < 112) wlds[tid] = NLOG2E * b1[tid - 96];

    // B-fragments of -log2e*W2 (loaded once): lane holds B[k=halfk*8+q][col=n*32+ln31]
    short8v w2f[2];
    float   b2c[2];
#pragma unroll
    for (int n = 0; n < 2; ++n) {
        const int col = n * 32 + ln31;
#pragma unroll
        for (int q = 0; q < 8; ++q)
            w2f[n][q] = (short)f2bf(NLOG2E * W2[(halfk * 8 + q) * 64 + col]);
        b2c[n] = NLOG2E * b2[col];
    }

    float S0 = 0.f, S1 = 0.f, SL = 0.f;

    __syncthreads();

    for (int t = g; t < NTILE; t += GPB) {
        // ---- Phase A/B: one face per thread: geometry + layer1 ----
        const int f      = t * TPB + tid;
        const bool valid = (f < NF_);
        const int fi     = valid ? f : 0;

        const int i0 = Fb[3 * fi + 0];
        const int i1 = Fb[3 * fi + 1];
        const int i2 = Fb[3 * fi + 2];

        const float* p0 = Vb + 3 * (size_t)i0;
        const float* p1 = Vb + 3 * (size_t)i1;
        const float* p2 = Vb + 3 * (size_t)i2;
        const float ax = p0[0], ay = p0[1], az = p0[2];
        const float bx = p1[0], by = p1[1], bz = p1[2];
        const float cx = p2[0], cy = p2[1], cz = p2[2];

        const float x0 = (ax + bx + cx) * (1.f / 3.f);
        const float x1 = (ay + by + cy) * (1.f / 3.f);
        const float x2 = (az + bz + cz) * (1.f / 3.f);

        const float e1x = bx - ax, e1y = by - ay, e1z = bz - az;
        const float e2x = cx - ax, e2y = cy - ay, e2z = cz - az;

        const float nx = 0.5f * (e1y * e2z - e1z * e2y);
        const float ny = 0.5f * (e1z * e2x - e1x * e2z);
        const float nz = 0.5f * (e1x * e2y - e1y * e2x);

        const float l2 = fmaxf(nx * nx + ny * ny + nz * nz, 1e-6f);
        const float rl = __builtin_amdgcn_rsqf(l2);
        const float L  = valid ? l2 * rl : 0.f;

        const float x3 = nx * rl, x4 = ny * rl, x5 = nz * rl;
        const float xs[6] = {x0, x1, x2, x3, x4, x5};

        short8v hrow[2];
#pragma unroll
        for (int q = 0; q < 4; ++q) {          // 4 channels per group
            float4 tq = *(const float4*)(wlds + 96 + q * 4);
#pragma unroll
            for (int d = 0; d < 6; ++d) {
                const float4 w = *(const float4*)(wlds + d * 16 + q * 4);
                tq.x = fmaf(xs[d], w.x, tq.x);
                tq.y = fmaf(xs[d], w.y, tq.y);
                tq.z = fmaf(xs[d], w.z, tq.z);
                tq.w = fmaf(xs[d], w.w, tq.w);
            }
            hrow[q >> 1][(q & 1) * 4 + 0] = (short)f2bf(fsig2(tq.x));
            hrow[q >> 1][(q & 1) * 4 + 1] = (short)f2bf(fsig2(tq.y));
            hrow[q >> 1][(q & 1) * 4 + 2] = (short)f2bf(fsig2(tq.z));
            hrow[q >> 1][(q & 1) * 4 + 3] = (short)f2bf(fsig2(tq.w));
        }
        ((short8v*)h1s)[tid * 2 + 0] = hrow[0];
        ((short8v*)h1s)[tid * 2 + 1] = hrow[1];
        sLs[tid] = L;
        SL += L;

        __syncthreads();

        // ---- Phase C: layer2 via MFMA. Wave owns faces wave*64..+63 ----
#pragma unroll
        for (int m = 0; m < 2; ++m) {
            const int rowbase = wave * 64 + m * 32;
            // A-fragment: row = rowbase+ln31, k-half = halfk
            short8v a = *(const short8v*)(h1s + (rowbase + ln31) * 16 + halfk * 8);

            f32x16 c0, c1;
#pragma unroll
            for (int r = 0; r < 16; ++r) { c0[r] = b2c[0]; c1[r] = b2c[1]; }
            c0 = __builtin_amdgcn_mfma_f32_32x32x16_bf16(a, w2f[0], c0, 0, 0, 0);
            c1 = __builtin_amdgcn_mfma_f32_32x32x16_bf16(a, w2f[1], c1, 0, 0, 0);

            // D row mapping: row = (r&3) + 8*(r>>2) + 4*halfk -> contiguous float4s
#pragma unroll
            for (int q = 0; q < 4; ++q) {
                const float4 Lq = *(const float4*)(sLs + rowbase + 8 * q + 4 * halfk);
                const float Lv[4] = {Lq.x, Lq.y, Lq.z, Lq.w};
#pragma unroll
                for (int s = 0; s < 4; ++s) {
                    const int r = q * 4 + s;
                    S0 = fmaf(fsig2(c0[r]), Lv[s], S0);
                    S1 = fmaf(fsig2(c1[r]), Lv[s], S1);
                }
            }
        }
        __syncthreads();   // protect h1s/sLs before next tile's writes
    }

    // ---- Block reduction ----
    // Channel c=n*32+ln31: lanes l and l+32 hold the same channel.
    S0 += __shfl_down(S0, 32, 64);
    S1 += __shfl_down(S1, 32, 64);
#pragma unroll
    for (int off = 32; off; off >>= 1)
        SL += __shfl_down(SL, off, 64);

    if (lane < 32) {
        red[wave][ln31]      = S0;
        red[wave][32 + ln31] = S1;
    }
    if (lane == 0) slred[wave] = SL;
    __syncthreads();

    if (tid < 64) {
        float s = red[0][tid] + red[1][tid] + red[2][tid] + red[3][tid];
        ws[((size_t)b * GPB + g) * 65 + tid] = s;
    }
    if (tid == 0)
        ws[((size_t)b * GPB + g) * 65 + 64] = slred[0] + slred[1] + slred[2] + slred[3];
}

// Kernel 2: fold the GPB partials through W3/b3. One block per batch.
__global__ __launch_bounds__(128) void finalize_out(
    const float* __restrict__ ws,  // [B, GPB, 65]
    const float* __restrict__ W3,  // [64, CCLS]
    const float* __restrict__ b3,  // [CCLS]
    float* __restrict__ out)       // [B, CCLS]
{
    __shared__ float sm[65];
    const int b = blockIdx.x;
    const int tid = threadIdx.x;

    if (tid < 65) {
        float s = 0.f;
#pragma unroll 8
        for (int g = 0; g < GPB; ++g)
            s += ws[((size_t)b * GPB + g) * 65 + tid];
        sm[tid] = s;
    }
    __syncthreads();

    if (tid < CCLS) {
        float acc = b3[tid] * sm[64];
#pragma unroll
        for (int k = 0; k < 64; ++k)
            acc = fmaf(sm[k], W3[k * CCLS + tid], acc);
        out[b * CCLS + tid] = acc;
    }
}

extern "C" void kernel_launch(void* const* d_in, const int* in_sizes, int n_in,
                              void* d_out, int out_size, void* d_ws, size_t ws_size,
                              hipStream_t stream) {
    const float* V  = (const float*)d_in[0];
    const int*   F  = (const int*)  d_in[1];
    const float* W1 = (const float*)d_in[2];
    const float* b1 = (const float*)d_in[3];
    const float* W2 = (const float*)d_in[4];
    const float* b2 = (const float*)d_in[5];
    const float* W3 = (const float*)d_in[6];
    const float* b3 = (const float*)d_in[7];
    float* out = (float*)d_out;
    float* ws  = (float*)d_ws;     // needs B*GPB*65*4 = 532,480 bytes

    face_mlp_partial<<<B_ * GPB, TPB, 0, stream>>>(V, F, W1, b1, W2, b2, ws);
    finalize_out<<<B_, 128, 0, stream>>>(ws, W3, b3, out);
}

// Round 5
// 105.512 us; speedup vs baseline: 3.0046x; 3.0046x over previous
//
#include <hip/hip_runtime.h>
#include <hip/hip_bf16.h>

// Problem constants (match reference)
#define B_    32
#define NV_   50000
#define NF_   100000
#define CCLS  40
#define GPB   64                       // blocks per batch
#define TPB   256
#define NTILE ((NF_ + TPB - 1) / TPB)  // 391 face-tiles per batch

#define NLOG2E (-1.44269504088896f)    // folded into pre-sigmoid weights

typedef __attribute__((ext_vector_type(8)))  short short8v;   // 8 bf16 = 4 VGPRs
typedef __attribute__((ext_vector_type(16))) float f32x16;    // MFMA 32x32 accum

// sigmoid with pre-scaled arg: t = -log2(e)*z  ->  sigma(z) = 1/(1+2^t)
__device__ __forceinline__ float fsig2(float t) {
    return __builtin_amdgcn_rcpf(1.0f + exp2f(t));
}

__device__ __forceinline__ ushort f2bf(float x) {
    __hip_bfloat16 h = __float2bfloat16(x);   // RNE
    return *reinterpret_cast<ushort*>(&h);
}

// Kernel 1: per 256-face tile: phase A (geometry + layer1 -> bf16 LDS, double-
// buffered), ONE barrier, phase C (layer2 on the matrix pipe, 32x32x16 bf16).
// Emits per-block partials ws[b][g][0..63]=sum sig(h2)[k]*L, ws[b][g][64]=sum L.
__global__ __launch_bounds__(TPB, 4) void face_mlp_partial(
    const float* __restrict__ V,   // [B,NV,3]
    const int*   __restrict__ F,   // [B,NF,3]
    const float* __restrict__ W1,  // [6,16]
    const float* __restrict__ b1,  // [16]
    const float* __restrict__ W2,  // [16,64]
    const float* __restrict__ b2,  // [64]
    float* __restrict__ ws)        // [B, GPB, 65]
{
    __shared__ __align__(16) ushort h1s[2][TPB * 16]; // bf16 h1, 32B/row, dbuf
    __shared__ __align__(16) float sLs[2][TPB];       // L per face, dbuf
    __shared__ __align__(16) float wlds[112];         // -log2e*{W1(96), b1(16)}
    __shared__ float red[4][64];
    __shared__ float slred[4];

    const int i   = blockIdx.x;
    // XCD-aware mapping: block i -> XCD (i&7); each XCD owns 4 batches so the
    // 4 x 600KB V-slices stay resident in its 4MB L2.
    const int xcd = i & 7;
    const int j   = i >> 3;
    const int b   = xcd + 8 * (j >> 6);
    const int g   = j & 63;
    const int tid = threadIdx.x;
    const int lane  = tid & 63;
    const int wave  = tid >> 6;
    const int ln31  = lane & 31;
    const int halfk = lane >> 5;       // k-half for A/B fragments

    const float* Vb = V + (size_t)b * NV_ * 3;
    const int*   Fb = F + (size_t)b * NF_ * 3;

    if (tid < 96)       wlds[tid] = NLOG2E * W1[tid];
    else if (tid < 112) wlds[tid] = NLOG2E * b1[tid - 96];

    // B-fragments of -log2e*W2 (loaded once): lane holds B[k=halfk*8+q][col=n*32+ln31]
    short8v w2f[2];
    float   b2c[2];
#pragma unroll
    for (int n = 0; n < 2; ++n) {
        const int col = n * 32 + ln31;
#pragma unroll
        for (int q = 0; q < 8; ++q)
            w2f[n][q] = (short)f2bf(NLOG2E * W2[(halfk * 8 + q) * 64 + col]);
        b2c[n] = NLOG2E * b2[col];
    }

    float S0 = 0.f, S1 = 0.f, SL = 0.f;

    __syncthreads();

    int buf = 0;
    for (int t = g; t < NTILE; t += GPB, buf ^= 1) {
        // ---- Phase A: one face per thread: geometry + layer1 -> LDS[buf] ----
        const int f      = t * TPB + tid;
        const bool valid = (f < NF_);
        const int fi     = valid ? f : 0;

        const int3 fidx = *(const int3*)(Fb + 3 * (size_t)fi);

        const float3 P0 = *(const float3*)(Vb + 3 * (size_t)fidx.x);
        const float3 P1 = *(const float3*)(Vb + 3 * (size_t)fidx.y);
        const float3 P2 = *(const float3*)(Vb + 3 * (size_t)fidx.z);

        const float x0 = (P0.x + P1.x + P2.x) * (1.f / 3.f);
        const float x1 = (P0.y + P1.y + P2.y) * (1.f / 3.f);
        const float x2 = (P0.z + P1.z + P2.z) * (1.f / 3.f);

        const float e1x = P1.x - P0.x, e1y = P1.y - P0.y, e1z = P1.z - P0.z;
        const float e2x = P2.x - P0.x, e2y = P2.y - P0.y, e2z = P2.z - P0.z;

        const float nx = 0.5f * (e1y * e2z - e1z * e2y);
        const float ny = 0.5f * (e1z * e2x - e1x * e2z);
        const float nz = 0.5f * (e1x * e2y - e1y * e2x);

        const float l2 = fmaxf(nx * nx + ny * ny + nz * nz, 1e-6f);
        const float rl = __builtin_amdgcn_rsqf(l2);
        const float L  = valid ? l2 * rl : 0.f;

        const float x3 = nx * rl, x4 = ny * rl, x5 = nz * rl;
        const float xs[6] = {x0, x1, x2, x3, x4, x5};

        short8v hrow[2];
#pragma unroll
        for (int q = 0; q < 4; ++q) {          // 4 channels per group
            float4 tq = *(const float4*)(wlds + 96 + q * 4);
#pragma unroll
            for (int d = 0; d < 6; ++d) {
                const float4 w = *(const float4*)(wlds + d * 16 + q * 4);
                tq.x = fmaf(xs[d], w.x, tq.x);
                tq.y = fmaf(xs[d], w.y, tq.y);
                tq.z = fmaf(xs[d], w.z, tq.z);
                tq.w = fmaf(xs[d], w.w, tq.w);
            }
            hrow[q >> 1][(q & 1) * 4 + 0] = (short)f2bf(fsig2(tq.x));
            hrow[q >> 1][(q & 1) * 4 + 1] = (short)f2bf(fsig2(tq.y));
            hrow[q >> 1][(q & 1) * 4 + 2] = (short)f2bf(fsig2(tq.z));
            hrow[q >> 1][(q & 1) * 4 + 3] = (short)f2bf(fsig2(tq.w));
        }
        ((short8v*)h1s[buf])[tid * 2 + 0] = hrow[0];
        ((short8v*)h1s[buf])[tid * 2 + 1] = hrow[1];
        sLs[buf][tid] = L;
        SL += L;

        __syncthreads();   // LDS[buf] writes visible; prev tile's phase C done
                           // racing-free: phase C below reads buf, next iter
                           // writes buf^1.

        // ---- Phase C: layer2 via MFMA. Wave owns faces wave*64..+63 ----
#pragma unroll
        for (int m = 0; m < 2; ++m) {
            const int rowbase = wave * 64 + m * 32;
            // A-fragment: row = rowbase+ln31, k-half = halfk
            short8v a = *(const short8v*)(h1s[buf] + (rowbase + ln31) * 16 + halfk * 8);

            f32x16 c0, c1;
#pragma unroll
            for (int r = 0; r < 16; ++r) { c0[r] = b2c[0]; c1[r] = b2c[1]; }
            c0 = __builtin_amdgcn_mfma_f32_32x32x16_bf16(a, w2f[0], c0, 0, 0, 0);
            c1 = __builtin_amdgcn_mfma_f32_32x32x16_bf16(a, w2f[1], c1, 0, 0, 0);

            // D row mapping: row = (r&3) + 8*(r>>2) + 4*halfk -> contiguous float4s
#pragma unroll
            for (int q = 0; q < 4; ++q) {
                const float4 Lq = *(const float4*)(&sLs[buf][rowbase + 8 * q + 4 * halfk]);
                const float Lv[4] = {Lq.x, Lq.y, Lq.z, Lq.w};
#pragma unroll
                for (int s = 0; s < 4; ++s) {
                    const int r = q * 4 + s;
                    S0 = fmaf(fsig2(c0[r]), Lv[s], S0);
                    S1 = fmaf(fsig2(c1[r]), Lv[s], S1);
                }
            }
        }
        // no second barrier: next iteration writes the other buffer
    }

    // ---- Block reduction ----
    // Channel c=n*32+ln31: lanes l and l+32 hold the same channel.
    S0 += __shfl_down(S0, 32, 64);
    S1 += __shfl_down(S1, 32, 64);
#pragma unroll
    for (int off = 32; off; off >>= 1)
        SL += __shfl_down(SL, off, 64);

    if (lane < 32) {
        red[wave][ln31]      = S0;
        red[wave][32 + ln31] = S1;
    }
    if (lane == 0) slred[wave] = SL;
    __syncthreads();

    if (tid < 64) {
        float s = red[0][tid] + red[1][tid] + red[2][tid] + red[3][tid];
        ws[((size_t)b * GPB + g) * 65 + tid] = s;
    }
    if (tid == 0)
        ws[((size_t)b * GPB + g) * 65 + 64] = slred[0] + slred[1] + slred[2] + slred[3];
}

// Kernel 2: fold the GPB partials through W3/b3. One block per batch.
__global__ __launch_bounds__(128) void finalize_out(
    const float* __restrict__ ws,  // [B, GPB, 65]
    const float* __restrict__ W3,  // [64, CCLS]
    const float* __restrict__ b3,  // [CCLS]
    float* __restrict__ out)       // [B, CCLS]
{
    __shared__ float sm[65];
    const int b = blockIdx.x;
    const int tid = threadIdx.x;

    if (tid < 65) {
        float s = 0.f;
#pragma unroll 8
        for (int g = 0; g < GPB; ++g)
            s += ws[((size_t)b * GPB + g) * 65 + tid];
        sm[tid] = s;
    }
    __syncthreads();

    if (tid < CCLS) {
        float acc = b3[tid] * sm[64];
#pragma unroll
        for (int k = 0; k < 64; ++k)
            acc = fmaf(sm[k], W3[k * CCLS + tid], acc);
        out[b * CCLS + tid] = acc;
    }
}

extern "C" void kernel_launch(void* const* d_in, const int* in_sizes, int n_in,
                              void* d_out, int out_size, void* d_ws, size_t ws_size,
                              hipStream_t stream) {
    const float* V  = (const float*)d_in[0];
    const int*   F  = (const int*)  d_in[1];
    const float* W1 = (const float*)d_in[2];
    const float* b1 = (const float*)d_in[3];
    const float* W2 = (const float*)d_in[4];
    const float* b2 = (const float*)d_in[5];
    const float* W3 = (const float*)d_in[6];
    const float* b3 = (const float*)d_in[7];
    float* out = (float*)d_out;
    float* ws  = (float*)d_ws;     // needs B*GPB*65*4 = 532,480 bytes

    face_mlp_partial<<<B_ * GPB, TPB, 0, stream>>>(V, F, W1, b1, W2, b2, ws);
    finalize_out<<<B_, 128, 0, stream>>>(ws, W3, b3, out);
}